// Round 5
// baseline (735.471 us; speedup 1.0000x reference)
//
#include <hip/hip_runtime.h>
#include <hip/hip_bf16.h>

// MultiheadAttention (heads=1): B=4, N=4096, D=512, PROJ=512. scale=0.125.
// Inputs fp32, output fp32. Internal: bf16 MFMA, fp32 accum.
//
// R5: flash_attn v3 — K/V fragments streamed DIRECTLY from global (L2/L3-resident,
// 8 MB/batch) into VGPRs; LDS only for Q (reused across all chunks) and the
// S->softmax->P exchange. 2 barriers per 128-key chunk (was ~8). 512 thr, 8 waves.
// GEMMs unchanged from R4 (128x128 tile, BK=64).

typedef __attribute__((ext_vector_type(8))) short bf16x8;
typedef __attribute__((ext_vector_type(4))) float f32x4;

#define NB 4
#define NN 4096
#define ND 512

__device__ __forceinline__ f32x4 mfma16(bf16x8 a, bf16x8 b, f32x4 c) {
    return __builtin_amdgcn_mfma_f32_16x16x32_bf16(a, b, c, 0, 0, 0);
}
__device__ __forceinline__ short f2bf(float f) {
    __hip_bfloat16 h = __float2bfloat16(f);
    return *reinterpret_cast<short*>(&h);
}

// ---------------- weight transpose: Wt[c][r] (bf16) = W[r][c] (fp32), 512x512 ----
struct Ptrs4 {
    const float* in[4];
    short* out[4];
};

__global__ void transpose_w(Ptrs4 p) {
    __shared__ short tile[32][33];
    const float* in = p.in[blockIdx.z];
    short* out = p.out[blockIdx.z];
    int r0 = blockIdx.y * 32, c0 = blockIdx.x * 32;
    int tx = threadIdx.x, ty = threadIdx.y;  // 32 x 8
    for (int i = 0; i < 32; i += 8)
        tile[ty + i][tx] = f2bf(in[(r0 + ty + i) * 512 + c0 + tx]);
    __syncthreads();
    for (int i = 0; i < 32; i += 8)
        out[(c0 + ty + i) * 512 + r0 + tx] = tile[tx][ty + i];
}

// ---------------- bt-form GEMM + bias, 128x128 tile, BK=64 (unchanged from R4) ----
template <int AF32, int VT, int OF32>
__global__ __launch_bounds__(256, 2) void gemm_bt_bias(
    const void* __restrict__ Av, const short* __restrict__ Bt,
    const float* __restrict__ bias, void* __restrict__ C) {
    __shared__ short As[128][72];
    __shared__ short Bs[128][72];
    int tid = threadIdx.x;
    int lane = tid & 63, w = tid >> 6;
    int l15 = lane & 15, l4 = lane >> 4;
    int wm = w & 1, wn = w >> 1;
    int m0 = blockIdx.y * 128, n0 = blockIdx.x * 128;
    f32x4 acc[4][4] = {};
    for (int kt = 0; kt < 512; kt += 64) {
        __syncthreads();
#pragma unroll
        for (int i = 0; i < 4; i++) {
            int vv = tid + i * 256;
            int row = vv >> 3, col8 = (vv & 7) * 8;
            if (AF32) {
                const float* A = (const float*)Av;
                const float* src = &A[(size_t)(m0 + row) * 512 + kt + col8];
                float4 f0 = *(const float4*)src;
                float4 f1 = *(const float4*)(src + 4);
                short tmp[8];
                tmp[0] = f2bf(f0.x); tmp[1] = f2bf(f0.y);
                tmp[2] = f2bf(f0.z); tmp[3] = f2bf(f0.w);
                tmp[4] = f2bf(f1.x); tmp[5] = f2bf(f1.y);
                tmp[6] = f2bf(f1.z); tmp[7] = f2bf(f1.w);
                *(bf16x8*)&As[row][col8] = *(bf16x8*)tmp;
            } else {
                const short* A = (const short*)Av;
                *(bf16x8*)&As[row][col8] = *(const bf16x8*)&A[(size_t)(m0 + row) * 512 + kt + col8];
            }
            *(bf16x8*)&Bs[row][col8] = *(const bf16x8*)&Bt[(size_t)(n0 + row) * 512 + kt + col8];
        }
        __syncthreads();
#pragma unroll
        for (int kb = 0; kb < 2; kb++) {
            int ko = kb * 32 + l4 * 8;
            bf16x8 af[4], bf[4];
#pragma unroll
            for (int t = 0; t < 4; t++) {
                af[t] = *(const bf16x8*)&As[wm * 64 + t * 16 + l15][ko];
                bf[t] = *(const bf16x8*)&Bs[wn * 64 + t * 16 + l15][ko];
            }
#pragma unroll
            for (int mt = 0; mt < 4; mt++)
#pragma unroll
                for (int nt = 0; nt < 4; nt++)
                    acc[mt][nt] = mfma16(af[mt], bf[nt], acc[mt][nt]);
        }
    }
#pragma unroll
    for (int mt = 0; mt < 4; mt++)
#pragma unroll
        for (int nt = 0; nt < 4; nt++) {
            f32x4 vv = acc[mt][nt];
            int col = n0 + wn * 64 + nt * 16 + l15;
            float bv = bias[col];
#pragma unroll
            for (int r = 0; r < 4; r++) {
                int row = m0 + wm * 64 + mt * 16 + l4 * 4 + r;
                float val = vv[r] + bv;
                if (VT) {
                    int b = row >> 12, j = row & 4095;
                    ((short*)C)[(size_t)b * (ND * NN) + (size_t)col * NN + j] = f2bf(val);
                } else if (OF32) {
                    ((float*)C)[(size_t)row * 512 + col] = val;
                } else {
                    ((short*)C)[(size_t)row * 512 + col] = f2bf(val);
                }
            }
        }
}

// ---------------- flash attention v3: global-streamed K/V frags ----------------
// Block: 64 Q-rows of one batch, 512 thr (8 waves). Tk=128 keys/chunk, 32 chunks.
// Wave w: wr=w&1 (q-rows 32*wr..+31, 2 tiles), wk=w>>1 (QK: key cols wk*32..+31;
// PV: e-cols wk*128..+127). K/V frags loaded straight from global (bt-form gather:
// 16 rows x 32B; kb-pairs make 128B/row contiguous -> L1 absorbs). 2 barriers/chunk.
// LDS: Qs[64][520] 66.5K | Sld[64][132]f32 33.8K | Pld[64][136] 17.4K | m/l/a 0.8K.
__global__ __launch_bounds__(512, 2) void flash_attn(
    const short* __restrict__ qp, const short* __restrict__ kp,
    const short* __restrict__ vpT, short* __restrict__ dpa) {
    __shared__ short Qs[64 * 520];
    __shared__ float Sld[64 * 132];
    __shared__ short Pld[64 * 136];
    __shared__ float mrow[64], lrow[64], arow[64];

    int tid = threadIdx.x;
    int lane = tid & 63, w = tid >> 6;
    int l15 = lane & 15, l4 = lane >> 4;
    int wr = w & 1;    // q half: rows wr*32 .. +31
    int wk = w >> 1;   // 0..3: QK key quarter (32) / PV e quarter (128)
    int b = blockIdx.y;
    int q0 = blockIdx.x * 64;

    const short* qpb = qp + (size_t)b * (NN * ND);
    const short* kpb = kp + (size_t)b * (NN * ND);
    const short* vtb = vpT + (size_t)b * (ND * NN);

    // stage Q tile to LDS: 64 rows x 512
#pragma unroll
    for (int i = 0; i < 8; i++) {
        int vv = tid + i * 512;
        int row = vv >> 6, col8 = (vv & 63) * 8;
        *(bf16x8*)&Qs[row * 520 + col8] = *(const bf16x8*)&qpb[(size_t)(q0 + row) * ND + col8];
    }
    if (tid < 64) { mrow[tid] = -1e30f; lrow[tid] = 0.f; }
    f32x4 oacc[2][8] = {};
    __syncthreads();

    for (int j0 = 0; j0 < NN; j0 += 128) {
        // ---- S = Q K^T : K frags direct from global ----
        f32x4 sacc[2][2] = {};
        const short* kbase = kpb + (size_t)(j0 + wk * 32) * ND;
#pragma unroll
        for (int kb2 = 0; kb2 < 8; kb2++) {
            bf16x8 kf[2][2], qf[2][2];
#pragma unroll
            for (int t = 0; t < 2; t++)
#pragma unroll
                for (int h = 0; h < 2; h++)
                    kf[t][h] = *(const bf16x8*)&kbase[(t * 16 + l15) * ND + (kb2 * 2 + h) * 32 + l4 * 8];
#pragma unroll
            for (int p = 0; p < 2; p++)
#pragma unroll
                for (int h = 0; h < 2; h++)
                    qf[p][h] = *(const bf16x8*)&Qs[(wr * 32 + p * 16 + l15) * 520 + (kb2 * 2 + h) * 32 + l4 * 8];
#pragma unroll
            for (int h = 0; h < 2; h++)
#pragma unroll
                for (int p = 0; p < 2; p++)
#pragma unroll
                    for (int t = 0; t < 2; t++)
                        sacc[p][t] = mfma16(qf[p][h], kf[t][h], sacc[p][t]);
        }
        // write scaled S (fp32) to LDS
#pragma unroll
        for (int p = 0; p < 2; p++)
#pragma unroll
            for (int t = 0; t < 2; t++)
#pragma unroll
                for (int r = 0; r < 4; r++)
                    Sld[(wr * 32 + p * 16 + l4 * 4 + r) * 132 + wk * 32 + t * 16 + l15] =
                        sacc[p][t][r] * 0.125f;
        __syncthreads();   // (1)
        // ---- online softmax: 8 threads/row, 16 cols each ----
        {
            int row = tid >> 3, c8 = tid & 7;
            float v[16];
            float mx = -1e30f;
#pragma unroll
            for (int i = 0; i < 16; i++) { v[i] = Sld[row * 132 + c8 * 16 + i]; mx = fmaxf(mx, v[i]); }
#pragma unroll
            for (int off = 1; off < 8; off <<= 1) mx = fmaxf(mx, __shfl_xor(mx, off));
            float mo = mrow[row];
            float mn = fmaxf(mo, mx);
            float ps = 0.f;
#pragma unroll
            for (int i = 0; i < 16; i++) { v[i] = __expf(v[i] - mn); ps += v[i]; }
#pragma unroll
            for (int off = 1; off < 8; off <<= 1) ps += __shfl_xor(ps, off);
            float al = __expf(mo - mn);
            if (c8 == 0) { mrow[row] = mn; lrow[row] = lrow[row] * al + ps; arow[row] = al; }
            short tmp[16];
#pragma unroll
            for (int i = 0; i < 16; i++) tmp[i] = f2bf(v[i]);
            *(bf16x8*)&Pld[row * 136 + c8 * 16] = *(bf16x8*)tmp;
            *(bf16x8*)&Pld[row * 136 + c8 * 16 + 8] = *(bf16x8*)&tmp[8];
        }
        __syncthreads();   // (2)
        // ---- rescale O by alpha; load P frags; V frags direct from global ----
        float al2[2][4];
#pragma unroll
        for (int p = 0; p < 2; p++)
#pragma unroll
            for (int r = 0; r < 4; r++) al2[p][r] = arow[wr * 32 + p * 16 + l4 * 4 + r];
#pragma unroll
        for (int p = 0; p < 2; p++)
#pragma unroll
            for (int et = 0; et < 8; et++)
#pragma unroll
                for (int r = 0; r < 4; r++) oacc[p][et][r] *= al2[p][r];
        bf16x8 pa[2][4];
#pragma unroll
        for (int p = 0; p < 2; p++)
#pragma unroll
            for (int kb = 0; kb < 4; kb++)
                pa[p][kb] = *(const bf16x8*)&Pld[(wr * 32 + p * 16 + l15) * 136 + kb * 32 + l4 * 8];
        const short* vbase = vtb + (size_t)(wk * 128) * NN + j0;
#pragma unroll
        for (int et = 0; et < 8; et++) {
            bf16x8 vf[4];
#pragma unroll
            for (int kb = 0; kb < 4; kb++)
                vf[kb] = *(const bf16x8*)&vbase[(size_t)(et * 16 + l15) * NN + kb * 32 + l4 * 8];
#pragma unroll
            for (int p = 0; p < 2; p++)
#pragma unroll
                for (int kb = 0; kb < 4; kb++)
                    oacc[p][et] = mfma16(pa[p][kb], vf[kb], oacc[p][et]);
        }
    }
    // ---- finalize: O /= l, store dpa (bf16) ----
    float li[2][4];
#pragma unroll
    for (int p = 0; p < 2; p++)
#pragma unroll
        for (int r = 0; r < 4; r++) li[p][r] = 1.f / lrow[wr * 32 + p * 16 + l4 * 4 + r];
    short* dpb = dpa + (size_t)b * (NN * ND);
#pragma unroll
    for (int p = 0; p < 2; p++)
#pragma unroll
        for (int et = 0; et < 8; et++) {
            int col = wk * 128 + et * 16 + l15;
#pragma unroll
            for (int r = 0; r < 4; r++) {
                int row = q0 + wr * 32 + p * 16 + l4 * 4 + r;
                dpb[(size_t)row * ND + col] = f2bf(oacc[p][et][r] * li[p][r]);
            }
        }
}

extern "C" void kernel_launch(void* const* d_in, const int* in_sizes, int n_in,
                              void* d_out, int out_size, void* d_ws, size_t ws_size,
                              hipStream_t stream) {
    const float* q     = (const float*)d_in[0];
    const float* k     = (const float*)d_in[1];
    const float* v     = (const float*)d_in[2];
    const float* w_q   = (const float*)d_in[3];
    const float* w_k   = (const float*)d_in[4];
    const float* w_v   = (const float*)d_in[5];
    const float* w_mha = (const float*)d_in[6];
    const float* b_q   = (const float*)d_in[7];
    const float* b_k   = (const float*)d_in[8];
    const float* b_v   = (const float*)d_in[9];
    const float* b_mha = (const float*)d_in[10];

    const size_t T = (size_t)NB * NN * ND;  // 8388608
    short* ws  = (short*)d_ws;
    short* qp  = ws;
    short* kp  = qp + T;
    short* vpT = kp + T;
    short* dpa = vpT + T;
    short* Wt  = dpa + T;  // 4 * 262144 shorts

    Ptrs4 p;
    p.in[0] = w_q;   p.out[0] = Wt;
    p.in[1] = w_k;   p.out[1] = Wt + 262144;
    p.in[2] = w_v;   p.out[2] = Wt + 524288;
    p.in[3] = w_mha; p.out[3] = Wt + 786432;
    transpose_w<<<dim3(16, 16, 4), dim3(32, 8), 0, stream>>>(p);

    gemm_bt_bias<1, 0, 0><<<dim3(4, 128), 256, 0, stream>>>(q, Wt,          b_q, qp);
    gemm_bt_bias<1, 0, 0><<<dim3(4, 128), 256, 0, stream>>>(k, Wt + 262144, b_k, kp);
    gemm_bt_bias<1, 1, 0><<<dim3(4, 128), 256, 0, stream>>>(v, Wt + 524288, b_v, vpT);

    flash_attn<<<dim3(64, 4), 512, 0, stream>>>(qp, kp, vpT, dpa);

    gemm_bt_bias<0, 0, 1><<<dim3(4, 128), 256, 0, stream>>>(dpa, Wt + 786432, b_mha, d_out);
}